// Round 8
// baseline (723.834 us; speedup 1.0000x reference)
//
#include <hip/hip_runtime.h>
#include <hip/hip_bf16.h>
#include <cmath>

#define T_ 1024
#define HID_ 2048
#define H_ 16
#define LQ_ 1536
#define LKV_ 512
#define DR_ 64
#define DN_ 128
#define DQ_ 192
#define DV_ 128
#define HI_ 16
#define DI_ 128
#define TOPK_ 256
#define NEGF (-1e30f)

typedef short bfrag_t __attribute__((ext_vector_type(8)));   // 8 bf16 = 4 VGPRs
typedef float f32x4 __attribute__((ext_vector_type(4)));

__device__ __forceinline__ float wave_sum64(float v) {
#pragma unroll
  for (int off = 32; off; off >>= 1) v += __shfl_xor(v, off);
  return v;
}

#define GLL(g, l) __builtin_amdgcn_global_load_lds((const __attribute__((address_space(1))) void*)(g), \
                                     (__attribute__((address_space(3))) void*)(l), 16, 0, 0)

// ================= bf16 MFMA GEMM: C = A @ B^T — double-buffered pipeline (verified R7) ====
template<typename CT>
__global__ __launch_bounds__(256) void gemm_bf_k(
    const short* __restrict__ A, int lda, long long sA,
    const short* __restrict__ B, int ldb, long long sB,
    CT* __restrict__ C, int ldc, long long sC,
    int Nout, int K)
{
  __shared__ short As[2][128 * 32];
  __shared__ short Bs[2][128 * 32];
  A += (long long)blockIdx.z * sA;
  B += (long long)blockIdx.z * sB;
  C += (long long)blockIdx.z * sC;
  const int tid = threadIdx.x;
  const int bm = blockIdx.y * 128, bn = blockIdx.x * 128;
  const int wave = tid >> 6, lane = tid & 63;
  const int wm = (wave >> 1) * 64, wn = (wave & 1) * 64;
  const int sr = tid >> 2;
  const int scol = (tid & 3) * 8;
  const int m0 = lane & 15, koff = (lane >> 4) * 8;
  f32x4 acc[4][4] = {};
  const short* ga = A + (long long)(bm + sr) * lda + scol;
  const short* gb = B + (long long)(bn + sr) * ldb + scol;
#define STAGE_BF(buf, off) \
    GLL(ga + (off), As[buf] + tid * 8); GLL(ga + (off) + 64 * lda, As[buf] + tid * 8 + 2048); \
    GLL(gb + (off), Bs[buf] + tid * 8); GLL(gb + (off) + 64 * ldb, Bs[buf] + tid * 8 + 2048);
  const int niter = K >> 5;
  STAGE_BF(0, 0);
  for (int it = 0; it < niter; ++it) {
    const int cur = it & 1;
    if (it + 1 < niter) {
      STAGE_BF(cur ^ 1, (it + 1) * 32);
      asm volatile("s_waitcnt vmcnt(4)\ns_barrier" ::: "memory");
    } else {
      asm volatile("s_waitcnt vmcnt(0)\ns_barrier" ::: "memory");
    }
    bfrag_t af[4], bfv[4];
#pragma unroll
    for (int i = 0; i < 4; ++i)
      af[i] = *(const bfrag_t*)(As[cur] + (wm + i * 16 + m0) * 32 + koff);
#pragma unroll
    for (int j = 0; j < 4; ++j)
      bfv[j] = *(const bfrag_t*)(Bs[cur] + (wn + j * 16 + m0) * 32 + koff);
#pragma unroll
    for (int i = 0; i < 4; ++i)
#pragma unroll
      for (int j = 0; j < 4; ++j)
        acc[i][j] = __builtin_amdgcn_mfma_f32_16x16x32_bf16(af[i], bfv[j], acc[i][j], 0, 0, 0);
    asm volatile("s_barrier" ::: "memory");
  }
#undef STAGE_BF
  const int cr = (lane >> 4) * 4, cc = lane & 15;
#pragma unroll
  for (int i = 0; i < 4; ++i) {
    int row = bm + wm + i * 16 + cr;
#pragma unroll
    for (int j = 0; j < 4; ++j) {
      int col = bn + wn + j * 16 + cc;
      if (col < Nout) {
#pragma unroll
        for (int r = 0; r < 4; ++r)
          C[(long long)(row + r) * ldc + col] = (CT)(acc[i][j][r]);
      }
    }
  }
}

// ====== bf16x3 split GEMM (fp32-accurate) — double-buffered pipeline (verified R7) ======
__global__ __launch_bounds__(256) void gemm3_k(
    const short* __restrict__ Ah, const short* __restrict__ Al, int lda,
    const short* __restrict__ Bh, const short* __restrict__ Bl, int ldb,
    float* __restrict__ C, int ldc, int Nout, int K)
{
  __shared__ short Ahs[2][128 * 32];
  __shared__ short Als[2][128 * 32];
  __shared__ short Bhs[2][128 * 32];
  __shared__ short Bls[2][128 * 32];
  const int tid = threadIdx.x;
  const int bm = blockIdx.y * 128, bn = blockIdx.x * 128;
  const int wave = tid >> 6, lane = tid & 63;
  const int wm = (wave >> 1) * 64, wn = (wave & 1) * 64;
  const int sr = tid >> 2;
  const int scol = (tid & 3) * 8;
  const int m0 = lane & 15, koff = (lane >> 4) * 8;
  f32x4 acc[4][4] = {};
  const short* gah = Ah + (long long)(bm + sr) * lda + scol;
  const short* gal = Al + (long long)(bm + sr) * lda + scol;
  const short* gbh = Bh + (long long)(bn + sr) * ldb + scol;
  const short* gbl = Bl + (long long)(bn + sr) * ldb + scol;
#define STAGE_3(buf, off) \
    GLL(gah + (off), Ahs[buf] + tid * 8); GLL(gah + (off) + 64 * lda, Ahs[buf] + tid * 8 + 2048); \
    GLL(gal + (off), Als[buf] + tid * 8); GLL(gal + (off) + 64 * lda, Als[buf] + tid * 8 + 2048); \
    GLL(gbh + (off), Bhs[buf] + tid * 8); GLL(gbh + (off) + 64 * ldb, Bhs[buf] + tid * 8 + 2048); \
    GLL(gbl + (off), Bls[buf] + tid * 8); GLL(gbl + (off) + 64 * ldb, Bls[buf] + tid * 8 + 2048);
  const int niter = K >> 5;
  STAGE_3(0, 0);
  for (int it = 0; it < niter; ++it) {
    const int cur = it & 1;
    if (it + 1 < niter) {
      STAGE_3(cur ^ 1, (it + 1) * 32);
      asm volatile("s_waitcnt vmcnt(8)\ns_barrier" ::: "memory");
    } else {
      asm volatile("s_waitcnt vmcnt(0)\ns_barrier" ::: "memory");
    }
    bfrag_t afh[4], afl[4], bfh[4], bfl[4];
#pragma unroll
    for (int i = 0; i < 4; ++i) {
      afh[i] = *(const bfrag_t*)(Ahs[cur] + (wm + i * 16 + m0) * 32 + koff);
      afl[i] = *(const bfrag_t*)(Als[cur] + (wm + i * 16 + m0) * 32 + koff);
    }
#pragma unroll
    for (int j = 0; j < 4; ++j) {
      bfh[j] = *(const bfrag_t*)(Bhs[cur] + (wn + j * 16 + m0) * 32 + koff);
      bfl[j] = *(const bfrag_t*)(Bls[cur] + (wn + j * 16 + m0) * 32 + koff);
    }
#pragma unroll
    for (int i = 0; i < 4; ++i)
#pragma unroll
      for (int j = 0; j < 4; ++j) {
        acc[i][j] = __builtin_amdgcn_mfma_f32_16x16x32_bf16(afh[i], bfh[j], acc[i][j], 0, 0, 0);
        acc[i][j] = __builtin_amdgcn_mfma_f32_16x16x32_bf16(afh[i], bfl[j], acc[i][j], 0, 0, 0);
        acc[i][j] = __builtin_amdgcn_mfma_f32_16x16x32_bf16(afl[i], bfh[j], acc[i][j], 0, 0, 0);
      }
    asm volatile("s_barrier" ::: "memory");
  }
#undef STAGE_3
  const int cr = (lane >> 4) * 4, cc = lane & 15;
#pragma unroll
  for (int i = 0; i < 4; ++i) {
    int row = bm + wm + i * 16 + cr;
#pragma unroll
    for (int j = 0; j < 4; ++j) {
      int col = bn + wn + j * 16 + cc;
      if (col < Nout) {
#pragma unroll
        for (int r = 0; r < 4; ++r)
          C[(long long)(row + r) * ldc + col] = acc[i][j][r];
      }
    }
  }
}

// ================= casts / decompose =================
__global__ __launch_bounds__(256) void cast_bf16_k(const float* __restrict__ src,
                                                   __hip_bfloat16* __restrict__ dst, int n4) {
  int i = blockIdx.x * 256 + threadIdx.x;
  if (i >= n4) return;
  float4 v = ((const float4*)src)[i];
  union { ushort4 u; __hip_bfloat16 h[4]; } o;
  o.h[0] = __float2bfloat16(v.x); o.h[1] = __float2bfloat16(v.y);
  o.h[2] = __float2bfloat16(v.z); o.h[3] = __float2bfloat16(v.w);
  ((ushort4*)dst)[i] = o.u;
}

__global__ __launch_bounds__(256) void decomp_k(const float* __restrict__ src,
                                                __hip_bfloat16* __restrict__ hi,
                                                __hip_bfloat16* __restrict__ lo, int n4) {
  int i = blockIdx.x * 256 + threadIdx.x;
  if (i >= n4) return;
  float4 v = ((const float4*)src)[i];
  float f[4] = {v.x, v.y, v.z, v.w};
  union { ushort4 u; __hip_bfloat16 h[4]; } oh, ol;
#pragma unroll
  for (int j = 0; j < 4; ++j) {
    __hip_bfloat16 h = __float2bfloat16(f[j]);
    oh.h[j] = h;
    ol.h[j] = __float2bfloat16(f[j] - __bfloat162float(h));
  }
  ((ushort4*)hi)[i] = oh.u;
  ((ushort4*)lo)[i] = ol.u;
}

__global__ __launch_bounds__(256) void cast_pad_k(const float* __restrict__ src,
                                                  __hip_bfloat16* __restrict__ dst,
                                                  int N, int K4, int Npad) {
  int i = blockIdx.x * 256 + threadIdx.x;
  if (i >= Npad * K4) return;
  int r = i / K4;
  float4 v = make_float4(0.f, 0.f, 0.f, 0.f);
  if (r < N) v = ((const float4*)src)[i];
  union { ushort4 u; __hip_bfloat16 h[4]; } o;
  o.h[0] = __float2bfloat16(v.x); o.h[1] = __float2bfloat16(v.y);
  o.h[2] = __float2bfloat16(v.z); o.h[3] = __float2bfloat16(v.w);
  ((ushort4*)dst)[i] = o.u;
}

// w_kn transposed-cast via LDS 64x64 tile (verified R7)
__global__ __launch_bounds__(256) void wkn_t_k(const float* __restrict__ wkvb,
                                               __hip_bfloat16* __restrict__ dst) {
  __shared__ float tile[64][65];
  const int h = blockIdx.z, k0 = blockIdx.y * 64, d0 = blockIdx.x * 64;
  const int c = threadIdx.x & 63, r0 = threadIdx.x >> 6;
#pragma unroll
  for (int rr = 0; rr < 16; ++rr) {
    int r = r0 + rr * 4;
    tile[r][c] = wkvb[((h * 256 + d0 + r) << 9) + k0 + c];
  }
  __syncthreads();
#pragma unroll
  for (int rr = 0; rr < 16; ++rr) {
    int r = r0 + rr * 4;
    dst[((h * 512 + k0 + r) << 7) + d0 + c] = __float2bfloat16(tile[c][r]);
  }
}

__global__ __launch_bounds__(256) void wv_cast_k(const float* __restrict__ wkvb,
                                                 __hip_bfloat16* __restrict__ dst) {
  int i = blockIdx.x * 256 + threadIdx.x;
  int k = i & 511, dv = (i >> 9) & 127, h = i >> 16;
  dst[i] = __float2bfloat16(wkvb[((h * 256 + 128 + dv) << 9) + k]);
}

// ================= RMSNorm in-place (fp32) =================
__global__ __launch_bounds__(256) void rms_inplace_k(float* x, const float* __restrict__ g,
                                                     int C) {
  int t = blockIdx.x, tid = threadIdx.x;
  float* row = x + (long long)t * C;
  float ss = 0.f;
  for (int i = tid; i < C; i += 256) { float v = row[i]; ss += v * v; }
  __shared__ float red[4];
  ss = wave_sum64(ss);
  if ((tid & 63) == 0) red[tid >> 6] = ss;
  __syncthreads();
  float sc = rsqrtf((red[0] + red[1] + red[2] + red[3]) / (float)C + 1e-6f);
  for (int i = tid; i < C; i += 256) row[i] = row[i] * sc * g[i];
}

// ================= skv build -> bf16; row T_ = 0 =================
__global__ __launch_bounds__(256) void skv_build_k(const float* __restrict__ ckv,
                                                   const float* __restrict__ g,
                                                   const float* __restrict__ cosb,
                                                   const float* __restrict__ sinb,
                                                   __hip_bfloat16* __restrict__ skv) {
  int t = blockIdx.x, tid = threadIdx.x;
  __hip_bfloat16* out = skv + (long long)t * 576;
  if (t == T_) { for (int i = tid; i < 576; i += 256) out[i] = __float2bfloat16(0.f); return; }
  const float* row = ckv + (long long)t * 576;
  float ss = 0.f;
  for (int i = tid; i < 512; i += 256) { float v = row[i]; ss += v * v; }
  __shared__ float red[4];
  ss = wave_sum64(ss);
  if ((tid & 63) == 0) red[tid >> 6] = ss;
  __syncthreads();
  float sc = rsqrtf((red[0] + red[1] + red[2] + red[3]) / 512.f + 1e-6f);
  for (int i = tid; i < 512; i += 256) out[i] = __float2bfloat16(row[i] * sc * g[i]);
  if (tid < 64) {
    int j = tid, j2 = tid & 31;
    float c = cosb[t * 64 + j], s = sinb[t * 64 + j];
    float a = row[512 + 2 * j2], b = row[512 + 2 * j2 + 1];
    out[512 + j] = __float2bfloat16((j < 32) ? (a * c - b * s) : (a * s + b * c));
  }
}

// ================= fused rope + hi/lo decompose on qi (one wave per head) =================
__global__ __launch_bounds__(256) void rope_decomp_qi_k(const float* __restrict__ qi,
                                                        __hip_bfloat16* __restrict__ hi,
                                                        __hip_bfloat16* __restrict__ lo,
                                                        const float* __restrict__ cosb,
                                                        const float* __restrict__ sinb) {
  int wave = threadIdx.x >> 6, lane = threadIdx.x & 63;
  int b = blockIdx.x * 4 + wave;           // head index in [0, T*HI)
  int t = b >> 4, j2 = lane & 31;
  const float* x = qi + (long long)b * DI_;
  float c = cosb[t * 64 + lane], s = sinb[t * 64 + lane];
  float a = x[2 * j2], bb = x[2 * j2 + 1];
  float v0 = (lane < 32) ? (a * c - bb * s) : (a * s + bb * c);  // rope'd col `lane`
  float v1 = x[64 + lane];                                       // passthrough col 64+lane
  __hip_bfloat16 h0 = __float2bfloat16(v0);
  __hip_bfloat16 h1 = __float2bfloat16(v1);
  hi[(long long)b * DI_ + lane] = h0;
  hi[(long long)b * DI_ + 64 + lane] = h1;
  lo[(long long)b * DI_ + lane] = __float2bfloat16(v0 - __bfloat162float(h0));
  lo[(long long)b * DI_ + 64 + lane] = __float2bfloat16(v1 - __bfloat162float(h1));
}

// ================= ki: LayerNorm + rope + hi/lo decompose (fused) =================
__global__ __launch_bounds__(128) void ki_ln_rope_k(const float* __restrict__ kbuf,
                                                    const float* __restrict__ w,
                                                    const float* __restrict__ bia,
                                                    const float* __restrict__ cosb,
                                                    const float* __restrict__ sinb,
                                                    __hip_bfloat16* __restrict__ hi,
                                                    __hip_bfloat16* __restrict__ lo) {
  int t = blockIdx.x, i = threadIdx.x;
  const float* row = kbuf + (long long)t * DI_;
  float x = row[i];
  __shared__ float red[2];
  float s1 = wave_sum64(x);
  if ((i & 63) == 0) red[i >> 6] = s1;
  __syncthreads();
  float mean = (red[0] + red[1]) / 128.f;
  float d = x - mean;
  __syncthreads();
  float s2 = wave_sum64(d * d);
  if ((i & 63) == 0) red[i >> 6] = s2;
  __syncthreads();
  float var = (red[0] + red[1]) / 128.f;
  float y = d * rsqrtf(var + 1e-6f) * w[i] + bia[i];
  __shared__ float rowl[128];
  rowl[i] = y;
  __syncthreads();
  float outv = y;
  if (i < 64) {
    int j2 = i & 31;
    float c = cosb[t * 64 + i], s = sinb[t * 64 + i];
    float a = rowl[2 * j2], b = rowl[2 * j2 + 1];
    outv = (i < 32) ? (a * c - b * s) : (a * s + b * c);
  }
  __hip_bfloat16 h = __float2bfloat16(outv);
  hi[t * DI_ + i] = h;
  lo[t * DI_ + i] = __float2bfloat16(outv - __bfloat162float(h));
}

// ================= rope q_full tail (bf16 in) -> sq_bf[...,512:576] =================
__global__ __launch_bounds__(64) void rope_q_sq_k(const __hip_bfloat16* __restrict__ qfull,
                                                  const float* __restrict__ cosb,
                                                  const float* __restrict__ sinb,
                                                  __hip_bfloat16* __restrict__ sq) {
  int b = blockIdx.x, t = b >> 4, h = b & 15, j = threadIdx.x, j2 = j & 31;
  const __hip_bfloat16* x = qfull + (long long)t * 3072 + h * 192 + 128;
  float c = cosb[t * 64 + j], s = sinb[t * 64 + j];
  float a = __bfloat162float(x[2 * j2]), bb = __bfloat162float(x[2 * j2 + 1]);
  float o = (j < 32) ? (a * c - bb * s) : (a * s + bb * c);
  sq[((long long)t * H_ + h) * 576 + 512 + j] = __float2bfloat16(o);
}

// ================= w = hidden @ i_wproj.T (fp32) =================
__global__ __launch_bounds__(256) void wproj_k(const float* __restrict__ hidden,
                                               const float* __restrict__ wp,
                                               float* __restrict__ out) {
  int wave = threadIdx.x >> 6, lane = threadIdx.x & 63;
  int t = blockIdx.x * 4 + wave;
  const float4* x4 = (const float4*)(hidden + (long long)t * 2048);
  float acc[16] = {};
  for (int c = lane; c < 512; c += 64) {
    float4 xv = x4[c];
#pragma unroll
    for (int h = 0; h < 16; ++h) {
      float4 wv = ((const float4*)(wp + h * 2048))[c];
      acc[h] += xv.x * wv.x + xv.y * wv.y + xv.z * wv.z + xv.w * wv.w;
    }
  }
#pragma unroll
  for (int h = 0; h < 16; ++h) {
    float s = wave_sum64(acc[h]);
    if (lane == 0) out[t * 16 + h] = s;
  }
}

// ================= indexer: MFMA bf16x3 scores + exact radix-select top-256 (verified R6) ===
__global__ __launch_bounds__(256) void score_topk_k(
    const short* __restrict__ qi_hi, const short* __restrict__ qi_lo,
    const short* __restrict__ ki_hi, const short* __restrict__ ki_lo,
    const float* __restrict__ wproj, const int* __restrict__ ks,
    const int* __restrict__ ke, int* __restrict__ indices)
{
  __shared__ float s_score[T_];
  __shared__ unsigned s_key[T_];
  __shared__ unsigned s_hist[256];
  __shared__ float s_w[HI_];
  __shared__ unsigned s_wsum[4];
  __shared__ unsigned s_binsel[2];
  __shared__ unsigned s_cnt;
  const int t = blockIdx.x, tid = threadIdx.x;
  const int wave = tid >> 6, lane = tid & 63;
  const int m0 = lane & 15, quad = lane >> 4;
  if (tid < HI_) s_w[tid] = wproj[t * HI_ + tid] * 0.022097086912079608f;
  if (tid == 0) s_cnt = 0;
  __syncthreads();

  bfrag_t ah[4], al[4];
  {
    const short* qh = qi_hi + ((long long)t * HI_ + m0) * DI_ + quad * 8;
    const short* ql = qi_lo + ((long long)t * HI_ + m0) * DI_ + quad * 8;
#pragma unroll
    for (int k = 0; k < 4; ++k) {
      ah[k] = *(const bfrag_t*)(qh + k * 32);
      al[k] = *(const bfrag_t*)(ql + k * 32);
    }
  }
  const int lo = ks[t], hi = ke[t];
  for (int tt = 0; tt < 16; ++tt) {
    const int n0 = wave * 256 + tt * 16;
    const short* kh = ki_hi + (n0 + m0) * DI_ + quad * 8;
    const short* kl = ki_lo + (n0 + m0) * DI_ + quad * 8;
    f32x4 acc = {0.f, 0.f, 0.f, 0.f};
#pragma unroll
    for (int k = 0; k < 4; ++k) {
      bfrag_t bh = *(const bfrag_t*)(kh + k * 32);
      bfrag_t bl = *(const bfrag_t*)(kl + k * 32);
      acc = __builtin_amdgcn_mfma_f32_16x16x32_bf16(ah[k], bh, acc, 0, 0, 0);
      acc = __builtin_amdgcn_mfma_f32_16x16x32_bf16(ah[k], bl, acc, 0, 0, 0);
      acc = __builtin_amdgcn_mfma_f32_16x16x32_bf16(al[k], bh, acc, 0, 0, 0);
    }
    float sc = 0.f;
#pragma unroll
    for (int r = 0; r < 4; ++r) sc += fmaxf(acc[r], 0.f) * s_w[quad * 4 + r];
    sc += __shfl_xor(sc, 16);
    sc += __shfl_xor(sc, 32);
    if (quad == 0) {
      int key = n0 + m0;
      s_score[key] = (key >= lo && key <= hi) ? sc : NEGF;
    }
  }
  __syncthreads();

  const int i0 = tid * 4;
#pragma unroll
  for (int j = 0; j < 4; ++j) {
    unsigned u = __float_as_uint(s_score[i0 + j]);
    s_key[i0 + j] = (u & 0x80000000u) ? ~u : (u | 0x80000000u);
  }
  __syncthreads();

  unsigned prefix = 0, Gprev = 0;
  for (int lvl = 0; lvl < 4; ++lvl) {
    const int shift = 24 - 8 * lvl;
    s_hist[tid] = 0;
    __syncthreads();
#pragma unroll
    for (int j = 0; j < 4; ++j) {
      unsigned k = s_key[i0 + j];
      if (lvl == 0 || (k >> (shift + 8)) == prefix)
        atomicAdd(&s_hist[(k >> shift) & 255u], 1u);
    }
    __syncthreads();
    unsigned h = s_hist[255 - tid];
    unsigned sc_ = h;
    for (int off = 1; off < 64; off <<= 1) {
      unsigned v = __shfl_up(sc_, off);
      if (lane >= off) sc_ += v;
    }
    if (lane == 63) s_wsum[wave] = sc_;
    __syncthreads();
    unsigned wo = 0;
    for (int w = 0; w < wave; ++w) wo += s_wsum[w];
    unsigned incl = sc_ + wo, excl = incl - h;
    unsigned Rn = 256 - Gprev;
    if (excl < Rn && Rn <= incl) { s_binsel[0] = 255 - (unsigned)tid; s_binsel[1] = excl; }
    __syncthreads();
    prefix = (prefix << 8) | s_binsel[0];
    Gprev += s_binsel[1];
  }
  const unsigned thr = prefix;
  const unsigned Rq = 256 - Gprev;
  const unsigned negfkey = ~__float_as_uint(NEGF);

  unsigned eqc = 0;
#pragma unroll
  for (int j = 0; j < 4; ++j) eqc += (s_key[i0 + j] == thr) ? 1u : 0u;
  unsigned esc = eqc;
  for (int off = 1; off < 64; off <<= 1) {
    unsigned v = __shfl_up(esc, off);
    if (lane >= off) esc += v;
  }
  if (lane == 63) s_wsum[wave] = esc;
  __syncthreads();
  unsigned eo = 0;
  for (int w = 0; w < wave; ++w) eo += s_wsum[w];
  unsigned rank = esc + eo - eqc;

#pragma unroll
  for (int j = 0; j < 4; ++j) {
    unsigned k = s_key[i0 + j];
    int outv = (k == negfkey) ? T_ : (i0 + j);
    if (k > thr) {
      unsigned slot = atomicAdd(&s_cnt, 1u);
      indices[t * TOPK_ + slot] = outv;
    } else if (k == thr) {
      if (rank < Rq) indices[t * TOPK_ + Gprev + rank] = outv;
      rank++;
    }
  }
}

// ================= MFMA gathered attention v3: 26 KB LDS -> 6 blocks/CU =================
// Phase 3: 16 rounds of (128-key half x 64-col chunk); s_vt[64][132]; register prefetch
#define SP_LD 257
#define PB_LD 264
#define VT_LD 132
__global__ __launch_bounds__(256, 6) void attn_k(
    const short* __restrict__ sq, const short* __restrict__ skv,
    const int* __restrict__ indices, __hip_bfloat16* __restrict__ attn_out)
{
  __shared__ int s_ind[TOPK_];
  __shared__ __align__(16) short s_pb[H_ * PB_LD];          // 8448 B
  __shared__ __align__(16) char s_un[64 * VT_LD * 2];       // 16896 B: s_p (16448) then s_vt
  float* s_p = (float*)s_un;
  short* s_vt = (short*)s_un;
  const int t = blockIdx.x, tid = threadIdx.x;
  const int wave = tid >> 6, lane = tid & 63;
  const int m0 = lane & 15, quad = lane >> 4;
  s_ind[tid] = indices[t * TOPK_ + tid];
  __syncthreads();

  // ---- phase 1: logits (per wave: 64 keys, gathered B-frags from L2) ----
  {
    const int jb = wave * 64;
    int rows[4];
    const short* kvp[4];
#pragma unroll
    for (int j = 0; j < 4; ++j) {
      rows[j] = s_ind[jb + j * 16 + m0];
      kvp[j] = skv + rows[j] * 576 + quad * 8;
    }
    const short* qp = sq + ((long long)t * H_ + m0) * 576 + quad * 8;
    f32x4 qacc[4] = {};
    for (int ks = 0; ks < 18; ++ks) {
      const int k0 = ks * 32;
      bfrag_t aq = *(const bfrag_t*)(qp + k0);
#pragma unroll
      for (int j = 0; j < 4; ++j) {
        bfrag_t bq = *(const bfrag_t*)(kvp[j] + k0);
        qacc[j] = __builtin_amdgcn_mfma_f32_16x16x32_bf16(aq, bq, qacc[j], 0, 0, 0);
      }
    }
    const float scale = 0.07216878364870322f;
#pragma unroll
    for (int j = 0; j < 4; ++j) {
      int key = jb + j * 16 + m0;
      bool msk = (rows[j] == T_);
#pragma unroll
      for (int r = 0; r < 4; ++r)
        s_p[(quad * 4 + r) * SP_LD + key] = msk ? NEGF : qacc[j][r] * scale;
    }
  }
  __syncthreads();

  // ---- phase 2: softmax ----
  for (int h = wave * 4; h < wave * 4 + 4; ++h) {
    float* ph = s_p + h * SP_LD;
    float m = -3.4e38f;
    for (int j = lane; j < TOPK_; j += 64) m = fmaxf(m, ph[j]);
#pragma unroll
    for (int off = 32; off; off >>= 1) m = fmaxf(m, __shfl_xor(m, off));
    float sum = 0.f;
    for (int j = lane; j < TOPK_; j += 64) {
      float e = __expf(ph[j] - m);
      ph[j] = e; sum += e;
    }
    sum = wave_sum64(sum);
    float inv = 1.f / sum;
    for (int j = lane; j < TOPK_; j += 64) ph[j] *= inv;
  }
  __syncthreads();

  // ---- P -> bf16 A-layout (s_pb survives; s_p dies after apf read barrier) ----
#pragma unroll
  for (int h = 0; h < H_; ++h)
    s_pb[h * PB_LD + tid] = (short)__bfloat16_as_ushort(__float2bfloat16(s_p[h * SP_LD + tid]));
  __syncthreads();

  bfrag_t apf[8];
#pragma unroll
  for (int kk = 0; kk < 8; ++kk)
    apf[kk] = *(const bfrag_t*)(s_pb + m0 * PB_LD + kk * 32 + quad * 8);

  // ---- phase 3: PV over 16 rounds = 8 col-chunks x 2 key-halves ----
  const int keyl = tid & 127;               // staged key (local to half)
  const int colhalf = (tid >> 7) * 32;      // this thread stages 32 cols
  const short* vsrc[2];
  vsrc[0] = skv + s_ind[keyl] * 576;
  vsrc[1] = skv + s_ind[128 + keyl] * 576;
  bfrag_t pf[4];
#pragma unroll
  for (int b = 0; b < 4; ++b) pf[b] = *(const bfrag_t*)(vsrc[0] + colhalf + b * 8);
  f32x4 oacc = {0.f, 0.f, 0.f, 0.f};
  for (int r = 0; r < 16; ++r) {
    const int half = r & 1, cc = r >> 1;
    __syncthreads();                         // s_vt (and round-0: dead s_p) free
#pragma unroll
    for (int b = 0; b < 4; ++b)
#pragma unroll
      for (int j = 0; j < 8; ++j)
        s_vt[(colhalf + b * 8 + j) * VT_LD + keyl] = pf[b][j];
    if (r + 1 < 16) {
      const int h2 = (r + 1) & 1, c2 = (r + 1) >> 1;
#pragma unroll
      for (int b = 0; b < 4; ++b)
        pf[b] = *(const bfrag_t*)(vsrc[h2] + c2 * 64 + colhalf + b * 8);
    }
    __syncthreads();                         // s_vt ready
    const short* vb = s_vt + (wave * 16 + m0) * VT_LD + quad * 8;
#pragma unroll
    for (int kk = 0; kk < 4; ++kk) {
      bfrag_t bv = *(const bfrag_t*)(vb + kk * 32);
      oacc = __builtin_amdgcn_mfma_f32_16x16x32_bf16(apf[half * 4 + kk], bv, oacc, 0, 0, 0);
    }
    if (half == 1) {
      const int col = cc * 64 + wave * 16 + m0;
#pragma unroll
      for (int rr = 0; rr < 4; ++rr)
        attn_out[((long long)t * H_ + quad * 4 + rr) * 512 + col] = __float2bfloat16(oacc[rr]);
      oacc = (f32x4){0.f, 0.f, 0.f, 0.f};
    }
  }
}

extern "C" void kernel_launch(void* const* d_in, const int* in_sizes, int n_in,
                              void* d_out, int out_size, void* d_ws, size_t ws_size,
                              hipStream_t stream) {
  const float* hidden  = (const float*)d_in[0];
  const float* cosb    = (const float*)d_in[1];
  const float* sinb    = (const float*)d_in[2];
  const int*   ks      = (const int*)d_in[3];
  const int*   ke      = (const int*)d_in[4];
  const float* w_qa    = (const float*)d_in[5];
  const float* g_qa    = (const float*)d_in[6];
  const float* w_qb    = (const float*)d_in[7];
  const float* w_kva   = (const float*)d_in[8];
  const float* g_kva   = (const float*)d_in[9];
  const float* w_kvb   = (const float*)d_in[10];
  const float* w_o     = (const float*)d_in[11];
  const float* i_wqb   = (const float*)d_in[12];
  const float* i_wk    = (const float*)d_in[13];
  const float* i_ln_w  = (const float*)d_in[14];
  const float* i_ln_b  = (const float*)d_in[15];
  const float* i_wproj = (const float*)d_in[16];
  float* out = (float*)d_out;
  (void)in_sizes; (void)n_in; (void)out_size; (void)ws_size;

  // ---- workspace (bytes), lifetime-overlapped (layout verified R6/R7) ----
  char* ws = (char*)d_ws;
  __hip_bfloat16* hid_hi  = (__hip_bfloat16*)(ws + 0);
  __hip_bfloat16* hid_lo  = (__hip_bfloat16*)(ws + 4194304);
  float*          q_lat   = (float*)(ws + 8388608);
  __hip_bfloat16* qi_hi   = (__hip_bfloat16*)(ws + 8388608);    // over dead q_lat
  __hip_bfloat16* qlat_hi = (__hip_bfloat16*)(ws + 14680064);
  __hip_bfloat16* qlat_lo = (__hip_bfloat16*)(ws + 17825792);
  float*          qi      = (float*)(ws + 20971520);
  float*          kib     = (float*)(ws + 29360128);
  float*          wbuf    = (float*)(ws + 29884416);
  float*          ckv     = (float*)(ws + 29949952);
  __hip_bfloat16* qi_lo   = (__hip_bfloat16*)(ws + 29949952);   // over dead ckv
  __hip_bfloat16* ki_hi   = (__hip_bfloat16*)(ws + 34144256);
  __hip_bfloat16* ki_lo   = (__hip_bfloat16*)(ws + 34406400);
  __hip_bfloat16* sq_bf   = (__hip_bfloat16*)(ws + 0);
  __hip_bfloat16* o_bf    = (__hip_bfloat16*)(ws + 0);
  __hip_bfloat16* W       = (__hip_bfloat16*)(ws + 37748736);
  __hip_bfloat16* skv_bf  = (__hip_bfloat16*)(ws + 47185920);
  int*            idxb    = (int*)(ws + 48366720);
  __hip_bfloat16* E       = (__hip_bfloat16*)(ws + 49415296);

  dim3 blk(256);
  const short* Ws = (const short*)W;
  const short* Es = (const short*)E;

  decomp_k<<<2048, blk, 0, stream>>>(hidden, hid_hi, hid_lo, 524288);

  decomp_k<<<3072, blk, 0, stream>>>(w_qa, W, E, 786432);
  gemm3_k<<<dim3(12, 8), blk, 0, stream>>>(
      (const short*)hid_hi, (const short*)hid_lo, HID_, Ws, Es, HID_, q_lat, LQ_, LQ_, HID_);
  rms_inplace_k<<<T_, blk, 0, stream>>>(q_lat, g_qa, LQ_);

  cast_pad_k<<<1280, blk, 0, stream>>>(w_kva, W, 576, 512, 640);
  gemm_bf_k<float><<<dim3(5, 8, 1), blk, 0, stream>>>(
      (const short*)hid_hi, HID_, 0, Ws, HID_, 0, ckv, 576, 0, 576, HID_);
  skv_build_k<<<T_ + 1, blk, 0, stream>>>(ckv, g_kva, cosb, sinb, skv_bf);

  decomp_k<<<1536, blk, 0, stream>>>(q_lat, qlat_hi, qlat_lo, 393216);

  decomp_k<<<3072, blk, 0, stream>>>(i_wqb, W, E, 786432);
  gemm3_k<<<dim3(16, 8), blk, 0, stream>>>(
      (const short*)qlat_hi, (const short*)qlat_lo, LQ_, Ws, Es, LQ_, qi, HI_ * DI_, HI_ * DI_, LQ_);
  rope_decomp_qi_k<<<T_ * HI_ / 4, blk, 0, stream>>>(qi, qi_hi, qi_lo, cosb, sinb);

  decomp_k<<<256, blk, 0, stream>>>(i_wk, W, E, 65536);
  gemm3_k<<<dim3(1, 8), blk, 0, stream>>>(
      (const short*)hid_hi, (const short*)hid_lo, HID_, Ws, Es, HID_, kib, DI_, DI_, HID_);
  ki_ln_rope_k<<<T_, dim3(128), 0, stream>>>(kib, i_ln_w, i_ln_b, cosb, sinb, ki_hi, ki_lo);

  wproj_k<<<256, blk, 0, stream>>>(hidden, i_wproj, wbuf);

  score_topk_k<<<T_, blk, 0, stream>>>(
      (const short*)qi_hi, (const short*)qi_lo, (const short*)ki_hi, (const short*)ki_lo,
      wbuf, ks, ke, idxb);

  cast_bf16_k<<<4608, blk, 0, stream>>>(w_qb, W, 1179648);
  gemm_bf_k<__hip_bfloat16><<<dim3(24, 8, 1), blk, 0, stream>>>(
      (const short*)qlat_hi, LQ_, 0, Ws, LQ_, 0, (__hip_bfloat16*)E, H_ * DQ_, 0, H_ * DQ_, LQ_);
  rope_q_sq_k<<<T_ * H_, dim3(64), 0, stream>>>(E, cosb, sinb, sq_bf);

  wkn_t_k<<<dim3(2, 8, 16), blk, 0, stream>>>(w_kvb, W);
  gemm_bf_k<__hip_bfloat16><<<dim3(4, 8, 16), blk, 0, stream>>>(
      Es, H_ * DQ_, 192, Ws, DI_, 65536, sq_bf, H_ * 576, 576, LKV_, DN_);

  attn_k<<<T_, blk, 0, stream>>>((const short*)sq_bf, (const short*)skv_bf, idxb, E);

  wv_cast_k<<<4096, blk, 0, stream>>>(w_kvb, W);
  gemm_bf_k<__hip_bfloat16><<<dim3(1, 8, 16), blk, 0, stream>>>(
      Es, H_ * LKV_, 512, Ws, LKV_, 65536, o_bf, H_ * DV_, 128, DV_, LKV_);

  cast_bf16_k<<<4096, blk, 0, stream>>>(w_o, W, 1048576);
  gemm_bf_k<float><<<dim3(16, 8, 1), blk, 0, stream>>>(
      (const short*)o_bf, H_ * DV_, 0, Ws, H_ * DV_, 0, out, HID_, 0, HID_, H_ * DV_);
}